// Round 1
// baseline (1631.643 us; speedup 1.0000x reference)
//
#include <hip/hip_runtime.h>
#include <math.h>

#define TS 256
#define HW 65536
#define CIN 64
#define EPSV 1e-5f

__device__ __forceinline__ float silu_f(float v){ return v / (1.0f + expf(-v)); }

// ---------------- transpose f[0]: (C,H,W) -> (H*W, C) ----------------
__global__ __launch_bounds__(256) void k_transpose(const float* __restrict__ x, float* __restrict__ fT){
    __shared__ float tile[64][65];
    int p0 = blockIdx.x * 64;
    int tid = threadIdx.x;
    int lane = tid & 63, grp = tid >> 6;
    #pragma unroll
    for (int k = 0; k < 16; ++k){
        int c = k*4 + grp;
        tile[lane][c] = x[c*HW + p0 + lane];
    }
    __syncthreads();
    #pragma unroll
    for (int k = 0; k < 16; ++k){
        int pp = k*4 + grp;
        fT[(p0 + pp)*64 + lane] = tile[pp][lane];
    }
}

// ---------------- offset conv (only channels selbase+0 and selbase+2; center p=1 is zeroed) ----------------
__global__ __launch_bounds__(256) void k_offset(const float* __restrict__ x, const float* __restrict__ ow,
        const float* __restrict__ ob, const float* __restrict__ og,
        const float* __restrict__ obb, const float* __restrict__ om,
        const float* __restrict__ ov, float* __restrict__ offm, int selbase){
    int b = blockIdx.y;
    int i = blockIdx.x;
    int j = threadIdx.x;
    int ch0 = selbase, ch2 = selbase + 2;
    float acc0 = 0.f, acc2 = 0.f;
    for (int c = 0; c < CIN; ++c){
        const float* xc = x + ((size_t)(b*CIN + c))*HW;
        #pragma unroll
        for (int dy = -1; dy <= 1; ++dy){
            int yy = i + dy;
            if (yy < 0 || yy >= TS) continue;
            #pragma unroll
            for (int dx = -1; dx <= 1; ++dx){
                int xx = j + dx;
                if (xx < 0 || xx >= TS) continue;
                float v = xc[yy*TS + xx];
                int r = (dy+1)*3 + (dx+1);
                acc0 += ow[(ch0*CIN + c)*9 + r] * v;
                acc2 += ow[(ch2*CIN + c)*9 + r] * v;
            }
        }
    }
    float s0 = og[ch0] * rsqrtf(ov[ch0] + EPSV);
    float val0 = (acc0 + ob[ch0]) * s0 + (obb[ch0] - om[ch0]*s0);
    float s2 = og[ch2] * rsqrtf(ov[ch2] + EPSV);
    float val2 = (acc2 + ob[ch2]) * s2 + (obb[ch2] - om[ch2]*s2);
    size_t base = ((size_t)(b*3)*TS + i)*TS + j;
    offm[base] = tanhf(val0);
    offm[base + (size_t)TS*TS] = 0.0f;
    offm[base + (size_t)2*TS*TS] = tanhf(val2);
}

// ---------------- conv0 3x3 same + BN + SiLU -> d_out ch [0,64) ----------------
__global__ __launch_bounds__(256) void k_conv0(const float* __restrict__ x, const float* __restrict__ w0,
        const float* __restrict__ g0, const float* __restrict__ b0,
        const float* __restrict__ m0, const float* __restrict__ v0,
        float* __restrict__ out){
    __shared__ __align__(16) float xt[8][18][18];
    __shared__ __align__(16) float wt[8][64][12];
    int b = blockIdx.y;
    int tile = blockIdx.x;
    int ty0 = (tile >> 4) * 16, tx0 = (tile & 15) * 16;
    int tid = threadIdx.x;
    int py = tid >> 4, px = tid & 15;
    float acc[64];
    #pragma unroll
    for (int o = 0; o < 64; ++o) acc[o] = 0.f;

    for (int cc = 0; cc < 8; ++cc){
        for (int idx = tid; idx < 8*18*18; idx += 256){
            int c = idx / 324; int rem = idx - c*324;
            int tyy = rem / 18, txx = rem - tyy*18;
            int gy = ty0 + tyy - 1, gx = tx0 + txx - 1;
            float v = 0.f;
            if (gy >= 0 && gy < TS && gx >= 0 && gx < TS)
                v = x[((size_t)(b*CIN + cc*8 + c))*HW + gy*TS + gx];
            xt[c][tyy][txx] = v;
        }
        for (int idx = tid; idx < 8*64*9; idx += 256){
            int c = idx / 576; int rem = idx - c*576;
            int o = rem / 9, r = rem - o*9;
            wt[c][o][r] = w0[(o*CIN + cc*8 + c)*9 + r];
        }
        __syncthreads();
        #pragma unroll
        for (int c = 0; c < 8; ++c){
            float n0 = xt[c][py+0][px+0], n1 = xt[c][py+0][px+1], n2 = xt[c][py+0][px+2];
            float n3 = xt[c][py+1][px+0], n4 = xt[c][py+1][px+1], n5 = xt[c][py+1][px+2];
            float n6 = xt[c][py+2][px+0], n7 = xt[c][py+2][px+1], n8 = xt[c][py+2][px+2];
            #pragma unroll
            for (int o = 0; o < 64; ++o){
                float4 wa = *(const float4*)&wt[c][o][0];
                float4 wb = *(const float4*)&wt[c][o][4];
                float w8 = wt[c][o][8];
                acc[o] += wa.x*n0 + wa.y*n1 + wa.z*n2 + wa.w*n3
                        + wb.x*n4 + wb.y*n5 + wb.z*n6 + wb.w*n7 + w8*n8;
            }
        }
        __syncthreads();
    }
    int gy = ty0 + py, gx = tx0 + px;
    #pragma unroll
    for (int o = 0; o < 64; ++o){
        float s = g0[o] * rsqrtf(v0[o] + EPSV);
        float v = acc[o]*s + (b0[o] - m0[o]*s);
        out[((size_t)(b*192 + o))*HW + gy*TS + gx] = silu_f(v);
    }
}

// ---------------- DSC: bilinear gather + strided conv; writes raw z (pre-GN) ----------------
template<int MORPH>
__global__ __launch_bounds__(256) void k_dsc(const float* __restrict__ fT, const float* __restrict__ offm,
        const float* __restrict__ w, const float* __restrict__ wb,
        float* __restrict__ out){
    __shared__ float Vt[96][64];
    __shared__ float wl[192][64];
    int b = blockIdx.z;
    int i = blockIdx.y;
    int j0 = blockIdx.x * 32;
    int tid = threadIdx.x;

    for (int idx = tid; idx < 192*64; idx += 256){
        int o = idx & 63; int cp = idx >> 6;
        int c = cp / 3, t = cp - c*3;
        wl[cp][o] = w[(o*64 + c)*3 + t];
    }

    int c = tid & 63;
    #pragma unroll
    for (int it = 0; it < 24; ++it){
        int pair = it*4 + (tid >> 6);
        float y, xf;
        if (MORPH == 0){
            int p = pair >> 5, jloc = pair & 31;
            int j = j0 + jloc;
            float off = offm[((size_t)(b*3 + p)*TS + i)*TS + j];
            y = (float)i + off;
            float vp = (p == 0) ? -2.0f : ((p == 1) ? -0.5f : 1.0f);
            xf = (float)i + vp;
        } else {
            int q = 3*j0 + pair;
            int p = q >> 8, jj = q & 255;
            float off = offm[((size_t)(b*3 + p)*TS + i)*TS + jj];
            float vp = (p == 0) ? -2.0f : ((p == 1) ? -0.5f : 1.0f);
            y = (float)i + vp + off;
            xf = (float)i;
        }
        float yf = floorf(y), xff = floorf(xf);
        float y0 = fminf(fmaxf(yf, 0.f), 255.f);
        float y1 = fminf(fmaxf(yf + 1.f, 0.f), 255.f);
        float x0 = fminf(fmaxf(xff, 0.f), 255.f);
        float x1 = fminf(fmaxf(xff + 1.f, 0.f), 255.f);
        float wy1 = y1 - y, wy0 = y - y0;
        float wx1 = x1 - xf, wx0 = xf - x0;
        int iy0 = (int)y0, iy1 = (int)y1, ix0 = (int)x0, ix1 = (int)x1;
        const float* f00 = fT + ((size_t)iy0*TS + ix0)*64;
        const float* f01 = fT + ((size_t)iy0*TS + ix1)*64;
        const float* f10 = fT + ((size_t)iy1*TS + ix0)*64;
        const float* f11 = fT + ((size_t)iy1*TS + ix1)*64;
        Vt[pair][c] = (wy1*wx1)*f00[c] + (wy1*wx0)*f01[c] + (wy0*wx1)*f10[c] + (wy0*wx0)*f11[c];
    }
    __syncthreads();

    int o = tid & 63, g = tid >> 6;
    float acc[8];
    #pragma unroll
    for (int jv = 0; jv < 8; ++jv) acc[jv] = 0.f;
    for (int cc = 0; cc < 64; ++cc){
        #pragma unroll
        for (int t = 0; t < 3; ++t){
            float wv = wl[cc*3 + t][o];
            #pragma unroll
            for (int jv = 0; jv < 8; ++jv){
                int jloc = g*8 + jv;
                int pidx = (MORPH == 0) ? (t*32 + jloc) : (3*jloc + t);
                acc[jv] += wv * Vt[pidx][cc];
            }
        }
    }
    float bias = wb[o];
    #pragma unroll
    for (int jv = 0; jv < 8; ++jv){
        int j = j0 + g*8 + jv;
        out[(size_t)b*192*HW + (size_t)o*HW + i*TS + j] = acc[jv] + bias;
    }
}

// ---------------- GN partial stats ----------------
__global__ __launch_bounds__(256) void k_gnpart(const float* __restrict__ dout, float* __restrict__ part){
    int bid = blockIdx.x;
    int slice = bid & 15;
    int g = (bid >> 4) & 15;
    int b = (bid >> 8) & 3;
    int m = bid >> 10;
    const float* base = dout + ((size_t)(b*192 + 64 + m*64 + g*4))*HW;
    float s = 0.f, ss = 0.f;
    for (int idx = threadIdx.x; idx < 16384; idx += 256){
        int ch = idx >> 12;
        int pix = slice*4096 + (idx & 4095);
        float v = base[(size_t)ch*HW + pix];
        s += v; ss += v*v;
    }
    __shared__ float rs[4], rss[4];
    #pragma unroll
    for (int d = 32; d > 0; d >>= 1){ s += __shfl_down(s, d, 64); ss += __shfl_down(ss, d, 64); }
    int lane = threadIdx.x & 63, wv = threadIdx.x >> 6;
    if (lane == 0){ rs[wv] = s; rss[wv] = ss; }
    __syncthreads();
    if (threadIdx.x == 0){
        part[bid*2]   = rs[0]+rs[1]+rs[2]+rs[3];
        part[bid*2+1] = rss[0]+rss[1]+rss[2]+rss[3];
    }
}

__global__ void k_gnfinal(const float* __restrict__ part, float* __restrict__ stats){
    int t = threadIdx.x;  // 128 = (m,b,g)
    float s = 0.f, ss = 0.f;
    for (int k = 0; k < 16; ++k){ s += part[(t*16+k)*2]; ss += part[(t*16+k)*2+1]; }
    float inv = 1.f/262144.f;
    float mean = s*inv;
    float var = ss*inv - mean*mean;
    stats[t*2] = mean;
    stats[t*2+1] = rsqrtf(var + EPSV);
}

__global__ __launch_bounds__(256) void k_gnapply(float* __restrict__ dout, const float* __restrict__ stats,
        const float* __restrict__ ggx, const float* __restrict__ gbx,
        const float* __restrict__ ggy, const float* __restrict__ gby){
    int idx = blockIdx.x*256 + threadIdx.x;   // 4*128*16384 float4
    int pix4 = idx & 16383;
    int chb = idx >> 14;
    int ch = chb & 127;
    int b = chb >> 7;
    int m = ch >> 6;
    int cc = ch & 63;
    int g = cc >> 2;
    const float* gg = m ? ggy : ggx;
    const float* gb = m ? gby : gbx;
    int si = ((m*4 + b)*16 + g)*2;
    float mean = stats[si], rsig = stats[si+1];
    float sc = rsig * gg[cc];
    float bi = gb[cc] - mean*sc;
    float4* ptr = (float4*)(dout + ((size_t)(b*192 + 64 + ch))*HW) + pix4;
    float4 v = *ptr;
    v.x = silu_f(v.x*sc + bi); v.y = silu_f(v.y*sc + bi);
    v.z = silu_f(v.z*sc + bi); v.w = silu_f(v.w*sc + bi);
    *ptr = v;
}

extern "C" void kernel_launch(void* const* d_in, const int* in_sizes, int n_in,
                              void* d_out, int out_size, void* d_ws, size_t ws_size,
                              hipStream_t stream){
    const float* x    = (const float*)d_in[0];
    const float* w0   = (const float*)d_in[1];
    const float* g0   = (const float*)d_in[2];
    const float* b0   = (const float*)d_in[3];
    const float* m0   = (const float*)d_in[4];
    const float* v0   = (const float*)d_in[5];
    const float* owx  = (const float*)d_in[6];
    const float* obx  = (const float*)d_in[7];
    const float* ogx  = (const float*)d_in[8];
    const float* obbx = (const float*)d_in[9];
    const float* omx  = (const float*)d_in[10];
    const float* ovx  = (const float*)d_in[11];
    const float* wx   = (const float*)d_in[12];
    const float* bwx  = (const float*)d_in[13];
    const float* ggx  = (const float*)d_in[14];
    const float* gbx  = (const float*)d_in[15];
    const float* owy  = (const float*)d_in[16];
    const float* oby  = (const float*)d_in[17];
    const float* ogy  = (const float*)d_in[18];
    const float* obby = (const float*)d_in[19];
    const float* omy  = (const float*)d_in[20];
    const float* ovy  = (const float*)d_in[21];
    const float* wy   = (const float*)d_in[22];
    const float* bwy  = (const float*)d_in[23];
    const float* ggy  = (const float*)d_in[24];
    const float* gby  = (const float*)d_in[25];

    float* out = (float*)d_out;
    float* ws = (float*)d_ws;
    float* fT   = ws;                    // 4194304
    float* off0 = fT + 4194304;          // 786432
    float* off1 = off0 + 786432;         // 786432
    float* part = off1 + 786432;         // 4096
    float* stats = part + 4096;          // 256

    k_transpose<<<1024, 256, 0, stream>>>(x, fT);
    k_offset<<<dim3(256,4), 256, 0, stream>>>(x, owx, obx, ogx, obbx, omx, ovx, off0, 0);
    k_offset<<<dim3(256,4), 256, 0, stream>>>(x, owy, oby, ogy, obby, omy, ovy, off1, 3);
    k_conv0<<<dim3(256,4), 256, 0, stream>>>(x, w0, g0, b0, m0, v0, out);
    k_dsc<0><<<dim3(8,256,4), 256, 0, stream>>>(fT, off0, wx, bwx, out + (size_t)64*HW);
    k_dsc<1><<<dim3(8,256,4), 256, 0, stream>>>(fT, off1, wy, bwy, out + (size_t)128*HW);
    k_gnpart<<<2048, 256, 0, stream>>>(out, part);
    k_gnfinal<<<1, 128, 0, stream>>>(part, stats);
    k_gnapply<<<32768, 256, 0, stream>>>(out, stats, ggx, gbx, ggy, gby);
}

// Round 2
// 1222.048 us; speedup vs baseline: 1.3352x; 1.3352x over previous
//
#include <hip/hip_runtime.h>
#include <hip/hip_bf16.h>
#include <math.h>

#define TS 256
#define HW 65536
#define CIN 64
#define EPSV 1e-5f
#define XPITCH 258   // padded row width (cols -1..256)

typedef __attribute__((ext_vector_type(8))) short bf16x8;
typedef __attribute__((ext_vector_type(4))) float f32x4;
typedef unsigned short ushort_t;

__device__ __forceinline__ float silu_f(float v){ return v / (1.0f + expf(-v)); }
__device__ __forceinline__ ushort_t f2bf(float f){
    __hip_bfloat16 h = __float2bfloat16(f);
    return *reinterpret_cast<ushort_t*>(&h);
}
__device__ __forceinline__ float bf2f(ushort_t u){
    unsigned int t = ((unsigned int)u) << 16;
    return __uint_as_float(t);
}

// ---------------- x (4,64,256,256) f32 -> xbf (4,256,258,64) bf16 (col-halo at j=-1,256) ----
__global__ __launch_bounds__(256) void k_xbf(const float* __restrict__ x, ushort_t* __restrict__ xbf){
    __shared__ float tile[64][65];
    int blk = blockIdx.x;
    int b = blk >> 10;
    int chunk = blk & 1023;
    int p0 = chunk * 64;           // 64 pixels, within one row (64 | 256)
    int i = p0 >> 8, jb = p0 & 255;
    int tid = threadIdx.x;
    int lane = tid & 63, grp = tid >> 6;
    #pragma unroll
    for (int k = 0; k < 16; ++k){
        int c = k*4 + grp;
        tile[lane][c] = x[((size_t)(b*CIN + c))*HW + p0 + lane];
    }
    __syncthreads();
    #pragma unroll
    for (int k = 0; k < 16; ++k){
        int pp = k*4 + grp;
        xbf[(((size_t)b*TS + i)*XPITCH + 1 + jb + pp)*64 + lane] = f2bf(tile[pp][lane]);
    }
}

__global__ void k_halo(ushort_t* __restrict__ xbf){
    int i = blockIdx.x, b = blockIdx.y, t = threadIdx.x;
    size_t rowbase = (((size_t)b*TS + i)*XPITCH)*64;
    if (t < 64) xbf[rowbase + t] = 0;                    // j = -1
    else        xbf[rowbase + (size_t)257*64 + (t-64)] = 0;  // j = 256
}

// ---------------- w0 (64o,64c,3,3) f32 -> w0bf (9r,64o,64c) bf16 ----------------
__global__ __launch_bounds__(256) void k_wrepack(const float* __restrict__ w0, ushort_t* __restrict__ w0bf){
    int idx = blockIdx.x*256 + threadIdx.x;   // 36864 total
    int r = idx >> 12;
    int rem = idx & 4095;
    int o = rem >> 6, c = rem & 63;
    w0bf[idx] = f2bf(w0[(o*64 + c)*9 + r]);
}

// ---------------- conv0 via MFMA: out[o][i][j] = sum_r sum_c W[r][o][c]*x[c][i+dy][j+dx] ----
__global__ __launch_bounds__(256) void k_conv0_mfma(
        const ushort_t* __restrict__ xbf, const ushort_t* __restrict__ w0bf,
        const float* __restrict__ g0, const float* __restrict__ b0,
        const float* __restrict__ m0, const float* __restrict__ v0,
        float* __restrict__ out){
    int b = blockIdx.y;
    int i = blockIdx.x;
    int wv = threadIdx.x >> 6;
    int lane = threadIdx.x & 63;
    int j0 = wv * 64;
    int l15 = lane & 15;
    int lhi = lane >> 4;            // 0..3
    f32x4 acc[4][4];
    #pragma unroll
    for (int mi = 0; mi < 4; ++mi)
        #pragma unroll
        for (int ni = 0; ni < 4; ++ni)
            acc[mi][ni] = (f32x4){0.f,0.f,0.f,0.f};

    for (int r = 0; r < 9; ++r){
        int dy = r/3 - 1, dx = r%3 - 1;
        int yy = i + dy;
        if (yy < 0 || yy >= TS) continue;
        const ushort_t* xrow = xbf + (((size_t)b*TS + yy)*XPITCH + 1)*64;
        const ushort_t* wrow = w0bf + (size_t)r*4096;
        #pragma unroll
        for (int kc = 0; kc < 2; ++kc){
            int c0 = kc*32 + lhi*8;
            bf16x8 af[4], bfr[4];
            #pragma unroll
            for (int mi = 0; mi < 4; ++mi)
                af[mi] = *(const bf16x8*)(wrow + (mi*16 + l15)*64 + c0);
            #pragma unroll
            for (int ni = 0; ni < 4; ++ni)
                bfr[ni] = *(const bf16x8*)(xrow + ((size_t)(j0 + ni*16 + l15 + dx))*64 + c0);
            #pragma unroll
            for (int mi = 0; mi < 4; ++mi)
                #pragma unroll
                for (int ni = 0; ni < 4; ++ni)
                    acc[mi][ni] = __builtin_amdgcn_mfma_f32_16x16x32_bf16(af[mi], bfr[ni], acc[mi][ni], 0, 0, 0);
        }
    }
    // epilogue: BN + SiLU; D layout: col=lane&15, row=(lane>>4)*4+reg
    #pragma unroll
    for (int mi = 0; mi < 4; ++mi){
        #pragma unroll
        for (int reg = 0; reg < 4; ++reg){
            int o = mi*16 + lhi*4 + reg;
            float s = g0[o] * rsqrtf(v0[o] + EPSV);
            float bi = b0[o] - m0[o]*s;
            #pragma unroll
            for (int ni = 0; ni < 4; ++ni){
                int j = j0 + ni*16 + l15;
                float v = acc[mi][ni][reg]*s + bi;
                out[((size_t)(b*192 + o))*HW + i*TS + j] = silu_f(v);
            }
        }
    }
}

// ---------------- offset conv (channels selbase+0, selbase+2; center plane zeroed) ----------------
__global__ __launch_bounds__(256) void k_offset(const float* __restrict__ x, const float* __restrict__ ow,
        const float* __restrict__ ob, const float* __restrict__ og,
        const float* __restrict__ obb, const float* __restrict__ om,
        const float* __restrict__ ov, float* __restrict__ offm, int selbase){
    int b = blockIdx.y;
    int i = blockIdx.x;
    int j = threadIdx.x;
    int ch0 = selbase, ch2 = selbase + 2;
    float acc0 = 0.f, acc2 = 0.f;
    for (int c = 0; c < CIN; ++c){
        const float* xc = x + ((size_t)(b*CIN + c))*HW;
        #pragma unroll
        for (int dy = -1; dy <= 1; ++dy){
            int yy = i + dy;
            if (yy < 0 || yy >= TS) continue;
            #pragma unroll
            for (int dx = -1; dx <= 1; ++dx){
                int xx = j + dx;
                if (xx < 0 || xx >= TS) continue;
                float v = xc[yy*TS + xx];
                int r = (dy+1)*3 + (dx+1);
                acc0 += ow[(ch0*CIN + c)*9 + r] * v;
                acc2 += ow[(ch2*CIN + c)*9 + r] * v;
            }
        }
    }
    float s0 = og[ch0] * rsqrtf(ov[ch0] + EPSV);
    float val0 = (acc0 + ob[ch0]) * s0 + (obb[ch0] - om[ch0]*s0);
    float s2 = og[ch2] * rsqrtf(ov[ch2] + EPSV);
    float val2 = (acc2 + ob[ch2]) * s2 + (obb[ch2] - om[ch2]*s2);
    size_t base = ((size_t)(b*3)*TS + i)*TS + j;
    offm[base] = tanhf(val0);
    offm[base + (size_t)TS*TS] = 0.0f;
    offm[base + (size_t)2*TS*TS] = tanhf(val2);
}

// ---------------- DSC: bilinear gather (from batch 0, bf16) + strided conv; writes raw z ----------------
template<int MORPH>
__global__ __launch_bounds__(256) void k_dsc(const ushort_t* __restrict__ xbf, const float* __restrict__ offm,
        const float* __restrict__ w, const float* __restrict__ wb,
        float* __restrict__ out){
    __shared__ float Vt[96][64];
    __shared__ float wl[192][64];
    int b = blockIdx.z;
    int i = blockIdx.y;
    int j0 = blockIdx.x * 32;
    int tid = threadIdx.x;

    for (int idx = tid; idx < 192*64; idx += 256){
        int o = idx & 63; int cp = idx >> 6;
        int c = cp / 3, t = cp - c*3;
        wl[cp][o] = w[(o*64 + c)*3 + t];
    }

    int c = tid & 63;
    #pragma unroll
    for (int it = 0; it < 24; ++it){
        int pair = it*4 + (tid >> 6);
        float y, xf;
        if (MORPH == 0){
            int p = pair >> 5, jloc = pair & 31;
            int j = j0 + jloc;
            float off = offm[((size_t)(b*3 + p)*TS + i)*TS + j];
            y = (float)i + off;
            float vp = (p == 0) ? -2.0f : ((p == 1) ? -0.5f : 1.0f);
            xf = (float)i + vp;
        } else {
            int q = 3*j0 + pair;
            int p = q >> 8, jj = q & 255;
            float off = offm[((size_t)(b*3 + p)*TS + i)*TS + jj];
            float vp = (p == 0) ? -2.0f : ((p == 1) ? -0.5f : 1.0f);
            y = (float)i + vp + off;
            xf = (float)i;
        }
        float yf = floorf(y), xff = floorf(xf);
        float y0 = fminf(fmaxf(yf, 0.f), 255.f);
        float y1 = fminf(fmaxf(yf + 1.f, 0.f), 255.f);
        float x0 = fminf(fmaxf(xff, 0.f), 255.f);
        float x1 = fminf(fmaxf(xff + 1.f, 0.f), 255.f);
        float wy1 = y1 - y, wy0 = y - y0;
        float wx1 = x1 - xf, wx0 = xf - x0;
        int iy0 = (int)y0, iy1 = (int)y1, ix0 = (int)x0, ix1 = (int)x1;
        const ushort_t* f00 = xbf + ((size_t)iy0*XPITCH + 1 + ix0)*64;
        const ushort_t* f01 = xbf + ((size_t)iy0*XPITCH + 1 + ix1)*64;
        const ushort_t* f10 = xbf + ((size_t)iy1*XPITCH + 1 + ix0)*64;
        const ushort_t* f11 = xbf + ((size_t)iy1*XPITCH + 1 + ix1)*64;
        Vt[pair][c] = (wy1*wx1)*bf2f(f00[c]) + (wy1*wx0)*bf2f(f01[c])
                    + (wy0*wx1)*bf2f(f10[c]) + (wy0*wx0)*bf2f(f11[c]);
    }
    __syncthreads();

    int o = tid & 63, g = tid >> 6;
    float acc[8];
    #pragma unroll
    for (int jv = 0; jv < 8; ++jv) acc[jv] = 0.f;
    for (int cc = 0; cc < 64; ++cc){
        #pragma unroll
        for (int t = 0; t < 3; ++t){
            float wv = wl[cc*3 + t][o];
            #pragma unroll
            for (int jv = 0; jv < 8; ++jv){
                int jloc = g*8 + jv;
                int pidx = (MORPH == 0) ? (t*32 + jloc) : (3*jloc + t);
                acc[jv] += wv * Vt[pidx][cc];
            }
        }
    }
    float bias = wb[o];
    #pragma unroll
    for (int jv = 0; jv < 8; ++jv){
        int j = j0 + g*8 + jv;
        out[(size_t)b*192*HW + (size_t)o*HW + i*TS + j] = acc[jv] + bias;
    }
}

// ---------------- GN partial stats ----------------
__global__ __launch_bounds__(256) void k_gnpart(const float* __restrict__ dout, float* __restrict__ part){
    int bid = blockIdx.x;
    int slice = bid & 15;
    int g = (bid >> 4) & 15;
    int b = (bid >> 8) & 3;
    int m = bid >> 10;
    const float* base = dout + ((size_t)(b*192 + 64 + m*64 + g*4))*HW;
    float s = 0.f, ss = 0.f;
    for (int idx = threadIdx.x; idx < 16384; idx += 256){
        int ch = idx >> 12;
        int pix = slice*4096 + (idx & 4095);
        float v = base[(size_t)ch*HW + pix];
        s += v; ss += v*v;
    }
    __shared__ float rs[4], rss[4];
    #pragma unroll
    for (int d = 32; d > 0; d >>= 1){ s += __shfl_down(s, d, 64); ss += __shfl_down(ss, d, 64); }
    int lane = threadIdx.x & 63, wv = threadIdx.x >> 6;
    if (lane == 0){ rs[wv] = s; rss[wv] = ss; }
    __syncthreads();
    if (threadIdx.x == 0){
        part[bid*2]   = rs[0]+rs[1]+rs[2]+rs[3];
        part[bid*2+1] = rss[0]+rss[1]+rss[2]+rss[3];
    }
}

__global__ void k_gnfinal(const float* __restrict__ part, float* __restrict__ stats){
    int t = threadIdx.x;  // 128 = (m,b,g)
    float s = 0.f, ss = 0.f;
    for (int k = 0; k < 16; ++k){ s += part[(t*16+k)*2]; ss += part[(t*16+k)*2+1]; }
    float inv = 1.f/262144.f;
    float mean = s*inv;
    float var = ss*inv - mean*mean;
    stats[t*2] = mean;
    stats[t*2+1] = rsqrtf(var + EPSV);
}

__global__ __launch_bounds__(256) void k_gnapply(float* __restrict__ dout, const float* __restrict__ stats,
        const float* __restrict__ ggx, const float* __restrict__ gbx,
        const float* __restrict__ ggy, const float* __restrict__ gby){
    int idx = blockIdx.x*256 + threadIdx.x;
    int pix4 = idx & 16383;
    int chb = idx >> 14;
    int ch = chb & 127;
    int b = chb >> 7;
    int m = ch >> 6;
    int cc = ch & 63;
    int g = cc >> 2;
    const float* gg = m ? ggy : ggx;
    const float* gb = m ? gby : gbx;
    int si = ((m*4 + b)*16 + g)*2;
    float mean = stats[si], rsig = stats[si+1];
    float sc = rsig * gg[cc];
    float bi = gb[cc] - mean*sc;
    float4* ptr = (float4*)(dout + ((size_t)(b*192 + 64 + ch))*HW) + pix4;
    float4 v = *ptr;
    v.x = silu_f(v.x*sc + bi); v.y = silu_f(v.y*sc + bi);
    v.z = silu_f(v.z*sc + bi); v.w = silu_f(v.w*sc + bi);
    *ptr = v;
}

extern "C" void kernel_launch(void* const* d_in, const int* in_sizes, int n_in,
                              void* d_out, int out_size, void* d_ws, size_t ws_size,
                              hipStream_t stream){
    const float* x    = (const float*)d_in[0];
    const float* w0   = (const float*)d_in[1];
    const float* g0   = (const float*)d_in[2];
    const float* b0   = (const float*)d_in[3];
    const float* m0   = (const float*)d_in[4];
    const float* v0   = (const float*)d_in[5];
    const float* owx  = (const float*)d_in[6];
    const float* obx  = (const float*)d_in[7];
    const float* ogx  = (const float*)d_in[8];
    const float* obbx = (const float*)d_in[9];
    const float* omx  = (const float*)d_in[10];
    const float* ovx  = (const float*)d_in[11];
    const float* wx   = (const float*)d_in[12];
    const float* bwx  = (const float*)d_in[13];
    const float* ggx  = (const float*)d_in[14];
    const float* gbx  = (const float*)d_in[15];
    const float* owy  = (const float*)d_in[16];
    const float* oby  = (const float*)d_in[17];
    const float* ogy  = (const float*)d_in[18];
    const float* obby = (const float*)d_in[19];
    const float* omy  = (const float*)d_in[20];
    const float* ovy  = (const float*)d_in[21];
    const float* wy   = (const float*)d_in[22];
    const float* bwy  = (const float*)d_in[23];
    const float* ggy  = (const float*)d_in[24];
    const float* gby  = (const float*)d_in[25];

    float* out = (float*)d_out;
    // ws layout (bytes): xbf 33,816,576 | w0bf 73,728 | off0/off1 | part | stats
    ushort_t* xbf  = (ushort_t*)d_ws;
    ushort_t* w0bf = xbf + (size_t)4*TS*XPITCH*64;         // 16,908,288 elems
    float* off0 = (float*)((char*)d_ws + 33890304);
    float* off1 = off0 + 786432;
    float* part = off1 + 786432;
    float* stats = part + 4096;

    k_xbf<<<4096, 256, 0, stream>>>(x, xbf);
    k_halo<<<dim3(256,4), 128, 0, stream>>>(xbf);
    k_wrepack<<<144, 256, 0, stream>>>(w0, w0bf);
    k_offset<<<dim3(256,4), 256, 0, stream>>>(x, owx, obx, ogx, obbx, omx, ovx, off0, 0);
    k_offset<<<dim3(256,4), 256, 0, stream>>>(x, owy, oby, ogy, obby, omy, ovy, off1, 3);
    k_conv0_mfma<<<dim3(256,4), 256, 0, stream>>>(xbf, w0bf, g0, b0, m0, v0, out);
    k_dsc<0><<<dim3(8,256,4), 256, 0, stream>>>(xbf, off0, wx, bwx, out + (size_t)64*HW);
    k_dsc<1><<<dim3(8,256,4), 256, 0, stream>>>(xbf, off1, wy, bwy, out + (size_t)128*HW);
    k_gnpart<<<2048, 256, 0, stream>>>(out, part);
    k_gnfinal<<<1, 128, 0, stream>>>(part, stats);
    k_gnapply<<<32768, 256, 0, stream>>>(out, stats, ggx, gbx, ggy, gby);
}

// Round 3
// 544.408 us; speedup vs baseline: 2.9971x; 2.2447x over previous
//
#include <hip/hip_runtime.h>
#include <hip/hip_bf16.h>
#include <math.h>

#define TS 256
#define HW 65536
#define CIN 64
#define EPSV 1e-5f
#define XPITCH 258   // padded row width (cols -1..256)

typedef __attribute__((ext_vector_type(8))) short bf16x8;
typedef __attribute__((ext_vector_type(4))) float f32x4;
typedef __attribute__((ext_vector_type(4))) unsigned short u16x4;
typedef unsigned short ushort_t;

__device__ __forceinline__ float silu_f(float v){ return v / (1.0f + expf(-v)); }
__device__ __forceinline__ ushort_t f2bf(float f){
    __hip_bfloat16 h = __float2bfloat16(f);
    return *reinterpret_cast<ushort_t*>(&h);
}
__device__ __forceinline__ float bf2f(ushort_t u){
    unsigned int t = ((unsigned int)u) << 16;
    return __uint_as_float(t);
}

// ---------------- x (4,64,256,256) f32 -> xbf (4,256,258,64) bf16 (col-halo at j=-1,256) ----
__global__ __launch_bounds__(256) void k_xbf(const float* __restrict__ x, ushort_t* __restrict__ xbf){
    __shared__ float tile[64][65];
    int blk = blockIdx.x;
    int b = blk >> 10;
    int chunk = blk & 1023;
    int p0 = chunk * 64;
    int i = p0 >> 8, jb = p0 & 255;
    int tid = threadIdx.x;
    int lane = tid & 63, grp = tid >> 6;
    #pragma unroll
    for (int k = 0; k < 16; ++k){
        int c = k*4 + grp;
        tile[lane][c] = x[((size_t)(b*CIN + c))*HW + p0 + lane];
    }
    __syncthreads();
    #pragma unroll
    for (int k = 0; k < 16; ++k){
        int pp = k*4 + grp;
        xbf[(((size_t)b*TS + i)*XPITCH + 1 + jb + pp)*64 + lane] = f2bf(tile[pp][lane]);
    }
}

__global__ void k_halo(ushort_t* __restrict__ xbf){
    int i = blockIdx.x, b = blockIdx.y, t = threadIdx.x;
    size_t rowbase = (((size_t)b*TS + i)*XPITCH)*64;
    if (t < 64) xbf[rowbase + t] = 0;
    else        xbf[rowbase + (size_t)257*64 + (t-64)] = 0;
}

// ---------------- w0 (64o,64c,3,3) f32 -> w0bf (9r,64o,64c) bf16 ----------------
__global__ __launch_bounds__(256) void k_wrepack(const float* __restrict__ w0, ushort_t* __restrict__ w0bf){
    int idx = blockIdx.x*256 + threadIdx.x;
    int r = idx >> 12;
    int rem = idx & 4095;
    int o = rem >> 6, c = rem & 63;
    w0bf[idx] = f2bf(w0[(o*64 + c)*9 + r]);
}

// ---------------- DSC weights: w (64o,64c,3t) f32 -> wbf (64o, t*64+c) bf16, both morphs ----
__global__ __launch_bounds__(256) void k_wdsc(const float* __restrict__ wx, const float* __restrict__ wy,
        ushort_t* __restrict__ wbfx, ushort_t* __restrict__ wbfy){
    int idx = blockIdx.x*256 + threadIdx.x;   // 24576
    int set = idx / 12288;
    int rem = idx - set*12288;
    int o = rem / 192;
    int k = rem - o*192;
    int t = k >> 6, c = k & 63;
    const float* w = set ? wy : wx;
    ushort_t* dst = set ? wbfy : wbfx;
    dst[rem] = f2bf(w[(o*64 + c)*3 + t]);
}

// ---------------- conv0 via MFMA ----
__global__ __launch_bounds__(256) void k_conv0_mfma(
        const ushort_t* __restrict__ xbf, const ushort_t* __restrict__ w0bf,
        const float* __restrict__ g0, const float* __restrict__ b0,
        const float* __restrict__ m0, const float* __restrict__ v0,
        float* __restrict__ out){
    int b = blockIdx.y;
    int i = blockIdx.x;
    int wv = threadIdx.x >> 6;
    int lane = threadIdx.x & 63;
    int j0 = wv * 64;
    int l15 = lane & 15;
    int lhi = lane >> 4;
    f32x4 acc[4][4];
    #pragma unroll
    for (int mi = 0; mi < 4; ++mi)
        #pragma unroll
        for (int ni = 0; ni < 4; ++ni)
            acc[mi][ni] = (f32x4){0.f,0.f,0.f,0.f};

    for (int r = 0; r < 9; ++r){
        int dy = r/3 - 1, dx = r%3 - 1;
        int yy = i + dy;
        if (yy < 0 || yy >= TS) continue;
        const ushort_t* xrow = xbf + (((size_t)b*TS + yy)*XPITCH + 1)*64;
        const ushort_t* wrow = w0bf + (size_t)r*4096;
        #pragma unroll
        for (int kc = 0; kc < 2; ++kc){
            int c0 = kc*32 + lhi*8;
            bf16x8 af[4], bfr[4];
            #pragma unroll
            for (int mi = 0; mi < 4; ++mi)
                af[mi] = *(const bf16x8*)(wrow + (mi*16 + l15)*64 + c0);
            #pragma unroll
            for (int ni = 0; ni < 4; ++ni)
                bfr[ni] = *(const bf16x8*)(xrow + ((size_t)(j0 + ni*16 + l15 + dx))*64 + c0);
            #pragma unroll
            for (int mi = 0; mi < 4; ++mi)
                #pragma unroll
                for (int ni = 0; ni < 4; ++ni)
                    acc[mi][ni] = __builtin_amdgcn_mfma_f32_16x16x32_bf16(af[mi], bfr[ni], acc[mi][ni], 0, 0, 0);
        }
    }
    #pragma unroll
    for (int mi = 0; mi < 4; ++mi){
        #pragma unroll
        for (int reg = 0; reg < 4; ++reg){
            int o = mi*16 + lhi*4 + reg;
            float s = g0[o] * rsqrtf(v0[o] + EPSV);
            float bi = b0[o] - m0[o]*s;
            #pragma unroll
            for (int ni = 0; ni < 4; ++ni){
                int j = j0 + ni*16 + l15;
                float v = acc[mi][ni][reg]*s + bi;
                out[((size_t)(b*192 + o))*HW + i*TS + j] = silu_f(v);
            }
        }
    }
}

// ---------------- offset conv (channels selbase+0, selbase+2) ----------------
__global__ __launch_bounds__(256) void k_offset(const float* __restrict__ x, const float* __restrict__ ow,
        const float* __restrict__ ob, const float* __restrict__ og,
        const float* __restrict__ obb, const float* __restrict__ om,
        const float* __restrict__ ov, float* __restrict__ offm, int selbase){
    int b = blockIdx.y;
    int i = blockIdx.x;
    int j = threadIdx.x;
    int ch0 = selbase, ch2 = selbase + 2;
    float acc0 = 0.f, acc2 = 0.f;
    for (int c = 0; c < CIN; ++c){
        const float* xc = x + ((size_t)(b*CIN + c))*HW;
        #pragma unroll
        for (int dy = -1; dy <= 1; ++dy){
            int yy = i + dy;
            if (yy < 0 || yy >= TS) continue;
            #pragma unroll
            for (int dx = -1; dx <= 1; ++dx){
                int xx = j + dx;
                if (xx < 0 || xx >= TS) continue;
                float v = xc[yy*TS + xx];
                int r = (dy+1)*3 + (dx+1);
                acc0 += ow[(ch0*CIN + c)*9 + r] * v;
                acc2 += ow[(ch2*CIN + c)*9 + r] * v;
            }
        }
    }
    float s0 = og[ch0] * rsqrtf(ov[ch0] + EPSV);
    float val0 = (acc0 + ob[ch0]) * s0 + (obb[ch0] - om[ch0]*s0);
    float s2 = og[ch2] * rsqrtf(ov[ch2] + EPSV);
    float val2 = (acc2 + ob[ch2]) * s2 + (obb[ch2] - om[ch2]*s2);
    size_t base = ((size_t)(b*3)*TS + i)*TS + j;
    offm[base] = tanhf(val0);
    offm[base + (size_t)TS*TS] = 0.0f;
    offm[base + (size_t)2*TS*TS] = tanhf(val2);
}

// ---------------- DSC: bilinear gather -> LDS bf16 -> MFMA (K=192 t-major) ----------------
template<int MORPH>
__global__ __launch_bounds__(256) void k_dsc2(const ushort_t* __restrict__ xbf, const float* __restrict__ offm,
        const ushort_t* __restrict__ wbf, const float* __restrict__ wb,
        float* __restrict__ outm){
    __shared__ __align__(16) ushort_t Vt[3*64*64];   // byte: t*8192 + j*128 + (c*2 ^ ((j&7)<<4))
    int b = blockIdx.z;
    int i = blockIdx.y;
    int j0 = blockIdx.x * 64;
    int tid = threadIdx.x;
    int lane16 = tid & 15;
    int pq = tid >> 4;
    const float fi = (float)i;

    #pragma unroll
    for (int it = 0; it < 12; ++it){
        int pair = it*16 + pq;
        int t = pair >> 6, jloc = pair & 63;
        float y, wx1, wx0;
        int x0i, x1i;
        if (MORPH == 0){
            int j = j0 + jloc;
            float off = offm[((size_t)(b*3 + t)*TS + i)*TS + j];
            y = fi + off;
            float vp = (t==0) ? -2.0f : ((t==1) ? -0.5f : 1.0f);
            float xf = fi + vp;
            float x0 = fminf(fmaxf(floorf(xf), 0.f), 255.f);
            float x1 = fminf(fmaxf(floorf(xf) + 1.f, 0.f), 255.f);
            wx1 = x1 - xf; wx0 = xf - x0;
            x0i = (int)x0; x1i = (int)x1;
        } else {
            int q = 3*(j0 + jloc) + t;
            int dl = q >> 8, jj = q & 255;
            float off = offm[((size_t)(b*3 + dl)*TS + i)*TS + jj];
            float vp = (dl==0) ? -2.0f : ((dl==1) ? -0.5f : 1.0f);
            y = fi + vp + off;
            wx1 = (i < 255) ? 1.f : 0.f; wx0 = 0.f;
            x0i = i; x1i = i;
        }
        float yf = floorf(y);
        float y0 = fminf(fmaxf(yf, 0.f), 255.f);
        float y1 = fminf(fmaxf(yf + 1.f, 0.f), 255.f);
        float wy1 = y1 - y, wy0 = y - y0;
        int y0i = (int)y0, y1i = (int)y1;
        int c0 = lane16*4;
        u16x4 a = *(const u16x4*)(xbf + ((size_t)y0i*XPITCH + 1 + x0i)*64 + c0);
        u16x4 c_ = *(const u16x4*)(xbf + ((size_t)y1i*XPITCH + 1 + x0i)*64 + c0);
        float v[4];
        if (MORPH == 0 && wx0 != 0.f){
            u16x4 bv = *(const u16x4*)(xbf + ((size_t)y0i*XPITCH + 1 + x1i)*64 + c0);
            u16x4 d  = *(const u16x4*)(xbf + ((size_t)y1i*XPITCH + 1 + x1i)*64 + c0);
            #pragma unroll
            for (int k = 0; k < 4; ++k)
                v[k] = wy1*(wx1*bf2f(a[k]) + wx0*bf2f(bv[k]))
                     + wy0*(wx1*bf2f(c_[k]) + wx0*bf2f(d[k]));
        } else {
            #pragma unroll
            for (int k = 0; k < 4; ++k)
                v[k] = wx1*(wy1*bf2f(a[k]) + wy0*bf2f(c_[k]));
        }
        unsigned int lo = (unsigned int)f2bf(v[0]) | ((unsigned int)f2bf(v[1]) << 16);
        unsigned int hi = (unsigned int)f2bf(v[2]) | ((unsigned int)f2bf(v[3]) << 16);
        int cbyte = (c0*2) ^ ((jloc & 7) << 4);
        uint2 pk; pk.x = lo; pk.y = hi;
        *(uint2*)((char*)Vt + t*8192 + jloc*128 + cbyte) = pk;
    }
    __syncthreads();

    int wv = tid >> 6;
    int lane = tid & 63;
    int l15 = lane & 15, lhi = lane >> 4;
    int mi = wv;
    f32x4 acc[4];
    #pragma unroll
    for (int ni = 0; ni < 4; ++ni) acc[ni] = (f32x4){0.f,0.f,0.f,0.f};
    bf16x8 af[6];
    #pragma unroll
    for (int ks = 0; ks < 6; ++ks)
        af[ks] = *(const bf16x8*)(wbf + (mi*16 + l15)*192 + ks*32 + lhi*8);
    #pragma unroll
    for (int ks = 0; ks < 6; ++ks){
        int t = ks >> 1;
        int cbyte = ((ks & 1)*32 + lhi*8)*2;
        #pragma unroll
        for (int ni = 0; ni < 4; ++ni){
            int j = ni*16 + l15;
            bf16x8 bfr = *(const bf16x8*)((char*)Vt + t*8192 + j*128 + (cbyte ^ ((j & 7) << 4)));
            acc[ni] = __builtin_amdgcn_mfma_f32_16x16x32_bf16(af[ks], bfr, acc[ni], 0, 0, 0);
        }
    }
    #pragma unroll
    for (int reg = 0; reg < 4; ++reg){
        int o = mi*16 + lhi*4 + reg;
        float bias = wb[o];
        #pragma unroll
        for (int ni = 0; ni < 4; ++ni){
            int j = j0 + ni*16 + l15;
            outm[(size_t)b*192*HW + (size_t)o*HW + i*TS + j] = acc[ni][reg] + bias;
        }
    }
}

// ---------------- GN partial stats ----------------
__global__ __launch_bounds__(256) void k_gnpart(const float* __restrict__ dout, float* __restrict__ part){
    int bid = blockIdx.x;
    int slice = bid & 15;
    int g = (bid >> 4) & 15;
    int b = (bid >> 8) & 3;
    int m = bid >> 10;
    const float* base = dout + ((size_t)(b*192 + 64 + m*64 + g*4))*HW;
    float s = 0.f, ss = 0.f;
    for (int idx = threadIdx.x; idx < 16384; idx += 256){
        int ch = idx >> 12;
        int pix = slice*4096 + (idx & 4095);
        float v = base[(size_t)ch*HW + pix];
        s += v; ss += v*v;
    }
    __shared__ float rs[4], rss[4];
    #pragma unroll
    for (int d = 32; d > 0; d >>= 1){ s += __shfl_down(s, d, 64); ss += __shfl_down(ss, d, 64); }
    int lane = threadIdx.x & 63, wv = threadIdx.x >> 6;
    if (lane == 0){ rs[wv] = s; rss[wv] = ss; }
    __syncthreads();
    if (threadIdx.x == 0){
        part[bid*2]   = rs[0]+rs[1]+rs[2]+rs[3];
        part[bid*2+1] = rss[0]+rss[1]+rss[2]+rss[3];
    }
}

__global__ void k_gnfinal(const float* __restrict__ part, float* __restrict__ stats){
    int t = threadIdx.x;
    float s = 0.f, ss = 0.f;
    for (int k = 0; k < 16; ++k){ s += part[(t*16+k)*2]; ss += part[(t*16+k)*2+1]; }
    float inv = 1.f/262144.f;
    float mean = s*inv;
    float var = ss*inv - mean*mean;
    stats[t*2] = mean;
    stats[t*2+1] = rsqrtf(var + EPSV);
}

__global__ __launch_bounds__(256) void k_gnapply(float* __restrict__ dout, const float* __restrict__ stats,
        const float* __restrict__ ggx, const float* __restrict__ gbx,
        const float* __restrict__ ggy, const float* __restrict__ gby){
    int idx = blockIdx.x*256 + threadIdx.x;
    int pix4 = idx & 16383;
    int chb = idx >> 14;
    int ch = chb & 127;
    int b = chb >> 7;
    int m = ch >> 6;
    int cc = ch & 63;
    int g = cc >> 2;
    const float* gg = m ? ggy : ggx;
    const float* gb = m ? gby : gbx;
    int si = ((m*4 + b)*16 + g)*2;
    float mean = stats[si], rsig = stats[si+1];
    float sc = rsig * gg[cc];
    float bi = gb[cc] - mean*sc;
    float4* ptr = (float4*)(dout + ((size_t)(b*192 + 64 + ch))*HW) + pix4;
    float4 v = *ptr;
    v.x = silu_f(v.x*sc + bi); v.y = silu_f(v.y*sc + bi);
    v.z = silu_f(v.z*sc + bi); v.w = silu_f(v.w*sc + bi);
    *ptr = v;
}

extern "C" void kernel_launch(void* const* d_in, const int* in_sizes, int n_in,
                              void* d_out, int out_size, void* d_ws, size_t ws_size,
                              hipStream_t stream){
    const float* x    = (const float*)d_in[0];
    const float* w0   = (const float*)d_in[1];
    const float* g0   = (const float*)d_in[2];
    const float* b0   = (const float*)d_in[3];
    const float* m0   = (const float*)d_in[4];
    const float* v0   = (const float*)d_in[5];
    const float* owx  = (const float*)d_in[6];
    const float* obx  = (const float*)d_in[7];
    const float* ogx  = (const float*)d_in[8];
    const float* obbx = (const float*)d_in[9];
    const float* omx  = (const float*)d_in[10];
    const float* ovx  = (const float*)d_in[11];
    const float* wx   = (const float*)d_in[12];
    const float* bwx  = (const float*)d_in[13];
    const float* ggx  = (const float*)d_in[14];
    const float* gbx  = (const float*)d_in[15];
    const float* owy  = (const float*)d_in[16];
    const float* oby  = (const float*)d_in[17];
    const float* ogy  = (const float*)d_in[18];
    const float* obby = (const float*)d_in[19];
    const float* omy  = (const float*)d_in[20];
    const float* ovy  = (const float*)d_in[21];
    const float* wy   = (const float*)d_in[22];
    const float* bwy  = (const float*)d_in[23];
    const float* ggy  = (const float*)d_in[24];
    const float* gby  = (const float*)d_in[25];

    float* out = (float*)d_out;
    // ws layout (bytes):
    //   xbf   @ 0          : 33,816,576
    //   w0bf  @ 33,816,576 : 73,728
    //   wbfx  @ 33,890,304 : 24,576
    //   wbfy  @ 33,914,880 : 24,576
    //   off0  @ 33,939,456 : 3,145,728
    //   off1  @ 37,085,184 : 3,145,728
    //   part  @ 40,230,912 : 16,384
    //   stats @ 40,247,296 : 1,024
    ushort_t* xbf  = (ushort_t*)d_ws;
    ushort_t* w0bf = (ushort_t*)((char*)d_ws + 33816576);
    ushort_t* wbfx = (ushort_t*)((char*)d_ws + 33890304);
    ushort_t* wbfy = (ushort_t*)((char*)d_ws + 33914880);
    float* off0  = (float*)((char*)d_ws + 33939456);
    float* off1  = (float*)((char*)d_ws + 37085184);
    float* part  = (float*)((char*)d_ws + 40230912);
    float* stats = (float*)((char*)d_ws + 40247296);

    k_xbf<<<4096, 256, 0, stream>>>(x, xbf);
    k_halo<<<dim3(256,4), 128, 0, stream>>>(xbf);
    k_wrepack<<<144, 256, 0, stream>>>(w0, w0bf);
    k_wdsc<<<96, 256, 0, stream>>>(wx, wy, wbfx, wbfy);
    k_offset<<<dim3(256,4), 256, 0, stream>>>(x, owx, obx, ogx, obbx, omx, ovx, off0, 0);
    k_offset<<<dim3(256,4), 256, 0, stream>>>(x, owy, oby, ogy, obby, omy, ovy, off1, 3);
    k_conv0_mfma<<<dim3(256,4), 256, 0, stream>>>(xbf, w0bf, g0, b0, m0, v0, out);
    k_dsc2<0><<<dim3(4,256,4), 256, 0, stream>>>(xbf, off0, wbfx, bwx, out + (size_t)64*HW);
    k_dsc2<1><<<dim3(4,256,4), 256, 0, stream>>>(xbf, off1, wbfy, bwy, out + (size_t)128*HW);
    k_gnpart<<<2048, 256, 0, stream>>>(out, part);
    k_gnfinal<<<1, 128, 0, stream>>>(part, stats);
    k_gnapply<<<32768, 256, 0, stream>>>(out, stats, ggx, gbx, ggy, gby);
}

// Round 5
// 360.468 us; speedup vs baseline: 4.5265x; 1.5103x over previous
//
#include <hip/hip_runtime.h>
#include <hip/hip_bf16.h>
#include <math.h>

#define TS 256
#define HW 65536
#define CIN 64
#define EPSV 1e-5f
#define XPITCH 258   // padded row width (cols -1..256)

typedef __attribute__((ext_vector_type(8))) short bf16x8;
typedef __attribute__((ext_vector_type(4))) float f32x4;
typedef __attribute__((ext_vector_type(4))) unsigned short u16x4;
typedef unsigned short ushort_t;

__device__ __forceinline__ float silu_f(float v){ return v / (1.0f + expf(-v)); }
__device__ __forceinline__ ushort_t f2bf(float f){
    __hip_bfloat16 h = __float2bfloat16(f);
    return *reinterpret_cast<ushort_t*>(&h);
}
__device__ __forceinline__ float bf2f(ushort_t u){
    unsigned int t = ((unsigned int)u) << 16;
    return __uint_as_float(t);
}

// ---------------- x (4,64,256,256) f32 -> xbf (4,256,258,64) bf16 (col-halo at j=-1,256) ----
__global__ __launch_bounds__(256) void k_xbf(const float* __restrict__ x, ushort_t* __restrict__ xbf){
    __shared__ float tile[64][65];
    int blk = blockIdx.x;
    int b = blk >> 10;
    int chunk = blk & 1023;
    int p0 = chunk * 64;
    int i = p0 >> 8, jb = p0 & 255;
    int tid = threadIdx.x;
    int lane = tid & 63, grp = tid >> 6;
    #pragma unroll
    for (int k = 0; k < 16; ++k){
        int c = k*4 + grp;
        tile[lane][c] = x[((size_t)(b*CIN + c))*HW + p0 + lane];
    }
    __syncthreads();
    #pragma unroll
    for (int k = 0; k < 16; ++k){
        int pp = k*4 + grp;
        xbf[(((size_t)b*TS + i)*XPITCH + 1 + jb + pp)*64 + lane] = f2bf(tile[pp][lane]);
    }
}

__global__ void k_halo(ushort_t* __restrict__ xbf){
    int i = blockIdx.x, b = blockIdx.y, t = threadIdx.x;
    size_t rowbase = (((size_t)b*TS + i)*XPITCH)*64;
    if (t < 64) xbf[rowbase + t] = 0;
    else        xbf[rowbase + (size_t)257*64 + (t-64)] = 0;
}

// ---------------- w0 (64o,64c,3,3) f32 -> w0bf (9r,64o,64c) bf16 ----------------
__global__ __launch_bounds__(256) void k_wrepack(const float* __restrict__ w0, ushort_t* __restrict__ w0bf){
    int idx = blockIdx.x*256 + threadIdx.x;
    int r = idx >> 12;
    int rem = idx & 4095;
    int o = rem >> 6, c = rem & 63;
    w0bf[idx] = f2bf(w0[(o*64 + c)*9 + r]);
}

// ---------------- DSC weights: w (64o,64c,3t) f32 -> wbf (64o, t*64+c) bf16, both morphs ----
__global__ __launch_bounds__(256) void k_wdsc(const float* __restrict__ wx, const float* __restrict__ wy,
        ushort_t* __restrict__ wbfx, ushort_t* __restrict__ wbfy){
    int idx = blockIdx.x*256 + threadIdx.x;   // 24576
    int set = idx / 12288;
    int rem = idx - set*12288;
    int o = rem / 192;
    int k = rem - o*192;
    int t = k >> 6, c = k & 63;
    const float* w = set ? wy : wx;
    ushort_t* dst = set ? wbfy : wbfx;
    dst[rem] = f2bf(w[(o*64 + c)*3 + t]);
}

// ---------------- conv0 via MFMA (round-3 verified version) ----
__global__ __launch_bounds__(256) void k_conv0_mfma(
        const ushort_t* __restrict__ xbf, const ushort_t* __restrict__ w0bf,
        const float* __restrict__ g0, const float* __restrict__ b0,
        const float* __restrict__ m0, const float* __restrict__ v0,
        float* __restrict__ out){
    int b = blockIdx.y;
    int i = blockIdx.x;
    int wv = threadIdx.x >> 6;
    int lane = threadIdx.x & 63;
    int j0 = wv * 64;
    int l15 = lane & 15;
    int lhi = lane >> 4;
    f32x4 acc[4][4];
    #pragma unroll
    for (int mi = 0; mi < 4; ++mi)
        #pragma unroll
        for (int ni = 0; ni < 4; ++ni)
            acc[mi][ni] = (f32x4){0.f,0.f,0.f,0.f};

    for (int r = 0; r < 9; ++r){
        int dy = r/3 - 1, dx = r%3 - 1;
        int yy = i + dy;
        if (yy < 0 || yy >= TS) continue;
        const ushort_t* xrow = xbf + (((size_t)b*TS + yy)*XPITCH + 1)*64;
        const ushort_t* wrow = w0bf + (size_t)r*4096;
        #pragma unroll
        for (int kc = 0; kc < 2; ++kc){
            int c0 = kc*32 + lhi*8;
            bf16x8 af[4], bfr[4];
            #pragma unroll
            for (int mi = 0; mi < 4; ++mi)
                af[mi] = *(const bf16x8*)(wrow + (mi*16 + l15)*64 + c0);
            #pragma unroll
            for (int ni = 0; ni < 4; ++ni)
                bfr[ni] = *(const bf16x8*)(xrow + ((size_t)(j0 + ni*16 + l15 + dx))*64 + c0);
            #pragma unroll
            for (int mi = 0; mi < 4; ++mi)
                #pragma unroll
                for (int ni = 0; ni < 4; ++ni)
                    acc[mi][ni] = __builtin_amdgcn_mfma_f32_16x16x32_bf16(af[mi], bfr[ni], acc[mi][ni], 0, 0, 0);
        }
    }
    #pragma unroll
    for (int mi = 0; mi < 4; ++mi){
        #pragma unroll
        for (int reg = 0; reg < 4; ++reg){
            int o = mi*16 + lhi*4 + reg;
            float s = g0[o] * rsqrtf(v0[o] + EPSV);
            float bi = b0[o] - m0[o]*s;
            #pragma unroll
            for (int ni = 0; ni < 4; ++ni){
                int j = j0 + ni*16 + l15;
                float v = acc[mi][ni][reg]*s + bi;
                out[((size_t)(b*192 + o))*HW + i*TS + j] = silu_f(v);
            }
        }
    }
}

// ---------------- both offset convs, exact f32, LDS-tiled; 2 output rows/block ----------------
__global__ __launch_bounds__(256) void k_offset2(const float* __restrict__ x,
        const float* __restrict__ owx, const float* __restrict__ obx,
        const float* __restrict__ ogx, const float* __restrict__ obbx,
        const float* __restrict__ omx, const float* __restrict__ ovx,
        const float* __restrict__ owy, const float* __restrict__ oby,
        const float* __restrict__ ogy, const float* __restrict__ obby,
        const float* __restrict__ omy, const float* __restrict__ ovy,
        float* __restrict__ off0, float* __restrict__ off1){
    __shared__ float xs[8][4][258];
    __shared__ float wsm[4][64][9];
    int b = blockIdx.y;
    int i0 = blockIdx.x * 2;
    int tid = threadIdx.x;
    // preload all 4 needed weight rows: 0:owx ch0, 1:owx ch2, 2:owy ch3, 3:owy ch5
    for (int idx = tid; idx < 2304; idx += 256){
        int o = idx / 576;
        int rem = idx - o*576;
        int c = rem / 9, tap = rem - c*9;
        int morph = o >> 1;
        int ch = (o==0)?0:(o==1)?2:(o==2)?3:5;
        const float* w = morph ? owy : owx;
        wsm[o][c][tap] = w[(ch*64 + c)*9 + tap];
    }
    float acc[4][2];
    #pragma unroll
    for (int o = 0; o < 4; ++o){ acc[o][0]=0.f; acc[o][1]=0.f; }
    __syncthreads();

    for (int cc = 0; cc < 8; ++cc){
        for (int idx = tid; idx < 8*4*258; idx += 256){
            int c = idx / 1032;
            int rem = idx - c*1032;
            int rr = rem / 258, col = rem - rr*258;
            int gy = i0 + rr - 1, gx = col - 1;
            float v = 0.f;
            if (gy >= 0 && gy < 256 && gx >= 0 && gx < 256)
                v = x[((size_t)(b*64 + cc*8 + c))*HW + gy*256 + gx];
            xs[c][rr][col] = v;
        }
        __syncthreads();
        int j = tid;
        #pragma unroll
        for (int c = 0; c < 8; ++c){
            float vrow[4][3];
            #pragma unroll
            for (int rr = 0; rr < 4; ++rr){
                vrow[rr][0] = xs[c][rr][j];
                vrow[rr][1] = xs[c][rr][j+1];
                vrow[rr][2] = xs[c][rr][j+2];
            }
            #pragma unroll
            for (int o = 0; o < 4; ++o){
                const float* wr = wsm[o][cc*8 + c];
                #pragma unroll
                for (int ky = 0; ky < 3; ++ky){
                    #pragma unroll
                    for (int kx = 0; kx < 3; ++kx){
                        float wv = wr[ky*3+kx];
                        acc[o][0] += wv * vrow[ky][kx];
                        acc[o][1] += wv * vrow[ky+1][kx];
                    }
                }
            }
        }
        __syncthreads();
    }
    #pragma unroll
    for (int o = 0; o < 4; ++o){
        int morph = o >> 1;
        int ch = (o==0)?0:(o==1)?2:(o==2)?3:5;
        int pl = (o & 1) ? 2 : 0;
        const float* og_ = morph? ogy:ogx; const float* ov_ = morph? ovy:ovx;
        const float* ob_ = morph? oby:obx; const float* om_ = morph? omy:omx;
        const float* obb_ = morph? obby:obbx;
        float s = og_[ch]*rsqrtf(ov_[ch]+EPSV);
        float bi = (ob_[ch]-om_[ch])*s + obb_[ch];
        float* base = (morph? off1:off0) + ((size_t)(b*3+pl)*TS)*TS;
        base[(size_t)i0*TS + tid]     = tanhf(acc[o][0]*s + bi);
        base[(size_t)(i0+1)*TS + tid] = tanhf(acc[o][1]*s + bi);
    }
    {
        float* c0p = off0 + ((size_t)(b*3+1)*TS)*TS;
        float* c1p = off1 + ((size_t)(b*3+1)*TS)*TS;
        c0p[(size_t)i0*TS + tid] = 0.f; c0p[(size_t)(i0+1)*TS + tid] = 0.f;
        c1p[(size_t)i0*TS + tid] = 0.f; c1p[(size_t)(i0+1)*TS + tid] = 0.f;
    }
}

// ---------------- DSC: bilinear gather -> LDS bf16 -> MFMA (K=192 t-major), fused GN partials ----
template<int MORPH>
__global__ __launch_bounds__(256) void k_dsc2(const ushort_t* __restrict__ xbf, const float* __restrict__ offm,
        const ushort_t* __restrict__ wbf, const float* __restrict__ wb,
        float* __restrict__ outm, float* __restrict__ part){
    __shared__ __align__(16) ushort_t Vt[3*64*64];   // byte: t*8192 + j*128 + (c*2 ^ ((j&7)<<4))
    int b = blockIdx.z;
    int i = blockIdx.y;
    int j0 = blockIdx.x * 64;
    int tid = threadIdx.x;
    int lane16 = tid & 15;
    int pq = tid >> 4;
    const float fi = (float)i;

    #pragma unroll
    for (int it = 0; it < 12; ++it){
        int pair = it*16 + pq;
        int t = pair >> 6, jloc = pair & 63;
        float y, wx1, wx0;
        int x0i, x1i;
        if (MORPH == 0){
            int j = j0 + jloc;
            float off = offm[((size_t)(b*3 + t)*TS + i)*TS + j];
            y = fi + off;
            float vp = (t==0) ? -2.0f : ((t==1) ? -0.5f : 1.0f);
            float xf = fi + vp;
            float x0 = fminf(fmaxf(floorf(xf), 0.f), 255.f);
            float x1 = fminf(fmaxf(floorf(xf) + 1.f, 0.f), 255.f);
            wx1 = x1 - xf; wx0 = xf - x0;
            x0i = (int)x0; x1i = (int)x1;
        } else {
            int q = 3*(j0 + jloc) + t;
            int dl = q >> 8, jj = q & 255;
            float off = offm[((size_t)(b*3 + dl)*TS + i)*TS + jj];
            float vp = (dl==0) ? -2.0f : ((dl==1) ? -0.5f : 1.0f);
            y = fi + vp + off;
            wx1 = (i < 255) ? 1.f : 0.f; wx0 = 0.f;
            x0i = i; x1i = i;
        }
        float yf = floorf(y);
        float y0 = fminf(fmaxf(yf, 0.f), 255.f);
        float y1 = fminf(fmaxf(yf + 1.f, 0.f), 255.f);
        float wy1 = y1 - y, wy0 = y - y0;
        int y0i = (int)y0, y1i = (int)y1;
        int c0 = lane16*4;
        u16x4 a = *(const u16x4*)(xbf + ((size_t)y0i*XPITCH + 1 + x0i)*64 + c0);
        u16x4 c_ = *(const u16x4*)(xbf + ((size_t)y1i*XPITCH + 1 + x0i)*64 + c0);
        float v[4];
        if (MORPH == 0 && wx0 != 0.f){
            u16x4 bv = *(const u16x4*)(xbf + ((size_t)y0i*XPITCH + 1 + x1i)*64 + c0);
            u16x4 d  = *(const u16x4*)(xbf + ((size_t)y1i*XPITCH + 1 + x1i)*64 + c0);
            #pragma unroll
            for (int k = 0; k < 4; ++k)
                v[k] = wy1*(wx1*bf2f(a[k]) + wx0*bf2f(bv[k]))
                     + wy0*(wx1*bf2f(c_[k]) + wx0*bf2f(d[k]));
        } else {
            #pragma unroll
            for (int k = 0; k < 4; ++k)
                v[k] = wx1*(wy1*bf2f(a[k]) + wy0*bf2f(c_[k]));
        }
        unsigned int lo = (unsigned int)f2bf(v[0]) | ((unsigned int)f2bf(v[1]) << 16);
        unsigned int hi = (unsigned int)f2bf(v[2]) | ((unsigned int)f2bf(v[3]) << 16);
        int cbyte = (c0*2) ^ ((jloc & 7) << 4);
        uint2 pk; pk.x = lo; pk.y = hi;
        *(uint2*)((char*)Vt + t*8192 + jloc*128 + cbyte) = pk;
    }
    __syncthreads();

    int wv = tid >> 6;
    int lane = tid & 63;
    int l15 = lane & 15, lhi = lane >> 4;
    int mi = wv;
    f32x4 acc[4];
    #pragma unroll
    for (int ni = 0; ni < 4; ++ni) acc[ni] = (f32x4){0.f,0.f,0.f,0.f};
    bf16x8 af[6];
    #pragma unroll
    for (int ks = 0; ks < 6; ++ks)
        af[ks] = *(const bf16x8*)(wbf + (mi*16 + l15)*192 + ks*32 + lhi*8);
    #pragma unroll
    for (int ks = 0; ks < 6; ++ks){
        int t = ks >> 1;
        int cbyte = ((ks & 1)*32 + lhi*8)*2;
        #pragma unroll
        for (int ni = 0; ni < 4; ++ni){
            int j = ni*16 + l15;
            bf16x8 bfr = *(const bf16x8*)((char*)Vt + t*8192 + j*128 + (cbyte ^ ((j & 7) << 4)));
            acc[ni] = __builtin_amdgcn_mfma_f32_16x16x32_bf16(af[ks], bfr, acc[ni], 0, 0, 0);
        }
    }
    float rsum[4], rsq[4];
    #pragma unroll
    for (int reg = 0; reg < 4; ++reg){
        int o = mi*16 + lhi*4 + reg;
        float bias = wb[o];
        float rs = 0.f, rq = 0.f;
        #pragma unroll
        for (int ni = 0; ni < 4; ++ni){
            int j = j0 + ni*16 + l15;
            float val = acc[ni][reg] + bias;
            outm[(size_t)b*192*HW + (size_t)o*HW + i*TS + j] = val;
            rs += val; rq += val*val;
        }
        #pragma unroll
        for (int m = 1; m < 16; m <<= 1){
            rs += __shfl_xor(rs, m, 64);
            rq += __shfl_xor(rq, m, 64);
        }
        rsum[reg] = rs; rsq[reg] = rq;
    }
    if (l15 == 0){
        float ts = rsum[0]+rsum[1]+rsum[2]+rsum[3];
        float tq = rsq[0]+rsq[1]+rsq[2]+rsq[3];
        int g = mi*4 + lhi;
        size_t slot = (((size_t)(MORPH*4 + b)*16 + g)*1024) + (blockIdx.y*4 + blockIdx.x);
        part[slot*2]   = ts;
        part[slot*2+1] = tq;
    }
}

// ---------------- GN final: reduce 1024 partials per (m,b,g) ----------------
__global__ __launch_bounds__(256) void k_gnfinal2(const float* __restrict__ part, float* __restrict__ stats){
    int slot = blockIdx.x;  // 0..127
    float s = 0.f, q = 0.f;
    for (int k = threadIdx.x; k < 1024; k += 256){
        s += part[((size_t)slot*1024 + k)*2];
        q += part[((size_t)slot*1024 + k)*2 + 1];
    }
    #pragma unroll
    for (int d = 32; d > 0; d >>= 1){ s += __shfl_down(s, d, 64); q += __shfl_down(q, d, 64); }
    __shared__ float rs[4], rq[4];
    int lane = threadIdx.x & 63, wv = threadIdx.x >> 6;
    if (lane == 0){ rs[wv] = s; rq[wv] = q; }
    __syncthreads();
    if (threadIdx.x == 0){
        float S = rs[0]+rs[1]+rs[2]+rs[3];
        float Q = rq[0]+rq[1]+rq[2]+rq[3];
        float inv = 1.f/262144.f;
        float mean = S*inv;
        float var = Q*inv - mean*mean;
        stats[slot*2] = mean;
        stats[slot*2+1] = rsqrtf(var + EPSV);
    }
}

__global__ __launch_bounds__(256) void k_gnapply(float* __restrict__ dout, const float* __restrict__ stats,
        const float* __restrict__ ggx, const float* __restrict__ gbx,
        const float* __restrict__ ggy, const float* __restrict__ gby){
    int idx = blockIdx.x*256 + threadIdx.x;
    int pix4 = idx & 16383;
    int chb = idx >> 14;
    int ch = chb & 127;
    int b = chb >> 7;
    int m = ch >> 6;
    int cc = ch & 63;
    int g = cc >> 2;
    const float* gg = m ? ggy : ggx;
    const float* gb = m ? gby : gbx;
    int si = ((m*4 + b)*16 + g)*2;
    float mean = stats[si], rsig = stats[si+1];
    float sc = rsig * gg[cc];
    float bi = gb[cc] - mean*sc;
    float4* ptr = (float4*)(dout + ((size_t)(b*192 + 64 + ch))*HW) + pix4;
    float4 v = *ptr;
    v.x = silu_f(v.x*sc + bi); v.y = silu_f(v.y*sc + bi);
    v.z = silu_f(v.z*sc + bi); v.w = silu_f(v.w*sc + bi);
    *ptr = v;
}

extern "C" void kernel_launch(void* const* d_in, const int* in_sizes, int n_in,
                              void* d_out, int out_size, void* d_ws, size_t ws_size,
                              hipStream_t stream){
    const float* x    = (const float*)d_in[0];
    const float* w0   = (const float*)d_in[1];
    const float* g0   = (const float*)d_in[2];
    const float* b0   = (const float*)d_in[3];
    const float* m0   = (const float*)d_in[4];
    const float* v0   = (const float*)d_in[5];
    const float* owx  = (const float*)d_in[6];
    const float* obx  = (const float*)d_in[7];
    const float* ogx  = (const float*)d_in[8];
    const float* obbx = (const float*)d_in[9];
    const float* omx  = (const float*)d_in[10];
    const float* ovx  = (const float*)d_in[11];
    const float* wx   = (const float*)d_in[12];
    const float* bwx  = (const float*)d_in[13];
    const float* ggx  = (const float*)d_in[14];
    const float* gbx  = (const float*)d_in[15];
    const float* owy  = (const float*)d_in[16];
    const float* oby  = (const float*)d_in[17];
    const float* ogy  = (const float*)d_in[18];
    const float* obby = (const float*)d_in[19];
    const float* omy  = (const float*)d_in[20];
    const float* ovy  = (const float*)d_in[21];
    const float* wy   = (const float*)d_in[22];
    const float* bwy  = (const float*)d_in[23];
    const float* ggy  = (const float*)d_in[24];
    const float* gby  = (const float*)d_in[25];

    float* out = (float*)d_out;
    // ws layout (bytes):
    //   xbf   @ 0          : 33,816,576
    //   w0bf  @ 33,816,576 : 73,728
    //   wbfx  @ 33,890,304 : 24,576
    //   wbfy  @ 33,914,880 : 24,576
    //   off0  @ 33,939,456 : 3,145,728
    //   off1  @ 37,085,184 : 3,145,728
    //   part  @ 40,230,912 : 1,048,576
    //   stats @ 41,279,488 : 1,024
    ushort_t* xbf  = (ushort_t*)d_ws;
    ushort_t* w0bf = (ushort_t*)((char*)d_ws + 33816576);
    ushort_t* wbfx = (ushort_t*)((char*)d_ws + 33890304);
    ushort_t* wbfy = (ushort_t*)((char*)d_ws + 33914880);
    float* off0  = (float*)((char*)d_ws + 33939456);
    float* off1  = (float*)((char*)d_ws + 37085184);
    float* part  = (float*)((char*)d_ws + 40230912);
    float* stats = (float*)((char*)d_ws + 41279488);

    k_xbf<<<4096, 256, 0, stream>>>(x, xbf);
    k_halo<<<dim3(256,4), 128, 0, stream>>>(xbf);
    k_wrepack<<<144, 256, 0, stream>>>(w0, w0bf);
    k_wdsc<<<96, 256, 0, stream>>>(wx, wy, wbfx, wbfy);
    k_offset2<<<dim3(128,4), 256, 0, stream>>>(x,
        owx, obx, ogx, obbx, omx, ovx,
        owy, oby, ogy, obby, omy, ovy,
        off0, off1);
    k_conv0_mfma<<<dim3(256,4), 256, 0, stream>>>(xbf, w0bf, g0, b0, m0, v0, out);
    k_dsc2<0><<<dim3(4,256,4), 256, 0, stream>>>(xbf, off0, wbfx, bwx, out + (size_t)64*HW, part);
    k_dsc2<1><<<dim3(4,256,4), 256, 0, stream>>>(xbf, off1, wbfy, bwy, out + (size_t)128*HW, part);
    k_gnfinal2<<<128, 256, 0, stream>>>(part, stats);
    k_gnapply<<<32768, 256, 0, stream>>>(out, stats, ggx, gbx, ggy, gby);
}

// Round 7
// 322.255 us; speedup vs baseline: 5.0632x; 1.1186x over previous
//
#include <hip/hip_runtime.h>
#include <hip/hip_bf16.h>
#include <math.h>

#define TS 256
#define HW 65536
#define CIN 64
#define EPSV 1e-5f
#define XPITCH 258   // padded row width (cols -1..256)

typedef __attribute__((ext_vector_type(8))) short bf16x8;
typedef __attribute__((ext_vector_type(4))) float f32x4;
typedef __attribute__((ext_vector_type(4))) unsigned short u16x4;
typedef unsigned short ushort_t;

__device__ __forceinline__ float silu_f(float v){ return v / (1.0f + expf(-v)); }
__device__ __forceinline__ ushort_t f2bf(float f){
    __hip_bfloat16 h = __float2bfloat16(f);
    return *reinterpret_cast<ushort_t*>(&h);
}
__device__ __forceinline__ float bf2f(ushort_t u){
    unsigned int t = ((unsigned int)u) << 16;
    return __uint_as_float(t);
}

// ---------------- x (4,64,256,256) f32 -> xbf (4,256,258,64) bf16 (col-halo at j=-1,256) ----
__global__ __launch_bounds__(256) void k_xbf(const float* __restrict__ x, ushort_t* __restrict__ xbf){
    __shared__ float tile[64][65];
    int blk = blockIdx.x;
    int b = blk >> 10;
    int chunk = blk & 1023;
    int p0 = chunk * 64;
    int i = p0 >> 8, jb = p0 & 255;
    int tid = threadIdx.x;
    int lane = tid & 63, grp = tid >> 6;
    #pragma unroll
    for (int k = 0; k < 16; ++k){
        int c = k*4 + grp;
        tile[lane][c] = x[((size_t)(b*CIN + c))*HW + p0 + lane];
    }
    __syncthreads();
    #pragma unroll
    for (int k = 0; k < 16; ++k){
        int pp = k*4 + grp;
        xbf[(((size_t)b*TS + i)*XPITCH + 1 + jb + pp)*64 + lane] = f2bf(tile[pp][lane]);
    }
}

__global__ void k_halo(ushort_t* __restrict__ xbf){
    int i = blockIdx.x, b = blockIdx.y, t = threadIdx.x;
    size_t rowbase = (((size_t)b*TS + i)*XPITCH)*64;
    if (t < 64) xbf[rowbase + t] = 0;
    else        xbf[rowbase + (size_t)257*64 + (t-64)] = 0;
}

// ---------------- w0 (64o,64c,3,3) f32 -> w0bf (9r,64o,64c) bf16 ----------------
__global__ __launch_bounds__(256) void k_wrepack(const float* __restrict__ w0, ushort_t* __restrict__ w0bf){
    int idx = blockIdx.x*256 + threadIdx.x;
    int r = idx >> 12;
    int rem = idx & 4095;
    int o = rem >> 6, c = rem & 63;
    w0bf[idx] = f2bf(w0[(o*64 + c)*9 + r]);
}

// ---------------- DSC weights: w (64o,64c,3t) f32 -> wbf (64o, t*64+c) bf16, both morphs ----
__global__ __launch_bounds__(256) void k_wdsc(const float* __restrict__ wx, const float* __restrict__ wy,
        ushort_t* __restrict__ wbfx, ushort_t* __restrict__ wbfy){
    int idx = blockIdx.x*256 + threadIdx.x;   // 24576
    int set = idx / 12288;
    int rem = idx - set*12288;
    int o = rem / 192;
    int k = rem - o*192;
    int t = k >> 6, c = k & 63;
    const float* w = set ? wy : wx;
    ushort_t* dst = set ? wbfy : wbfx;
    dst[rem] = f2bf(w[(o*64 + c)*3 + t]);
}

// ---------------- offset conv partials: 8-ch chunk, 2 output rows, exact f32 ----------------
__global__ __launch_bounds__(256) void k_offp(const float* __restrict__ x,
        const float* __restrict__ owx, const float* __restrict__ owy,
        float* __restrict__ poff){
    __shared__ float xs[8][4][258];
    __shared__ float wsm[4][8][9];
    int by = blockIdx.y;          // b*8 + chunk
    int b = by >> 3, chunk = by & 7;
    int i0 = blockIdx.x * 2;
    int tid = threadIdx.x;
    // weights: 4 rows {owx ch0, owx ch2, owy ch3, owy ch5}, channels chunk*8..+7
    for (int idx = tid; idx < 4*8*9; idx += 256){
        int o = idx / 72;
        int rem = idx - o*72;
        int c = rem / 9, tap = rem - c*9;
        int morph = o >> 1;
        int ch = (o==0)?0:(o==1)?2:(o==2)?3:5;
        const float* w = morph ? owy : owx;
        wsm[o][c][tap] = w[(ch*64 + chunk*8 + c)*9 + tap];
    }
    // x tile: 8 ch x 4 rows x 258 cols
    for (int idx = tid; idx < 8*4*258; idx += 256){
        int c = idx / 1032;
        int rem = idx - c*1032;
        int rr = rem / 258, col = rem - rr*258;
        int gy = i0 + rr - 1, gx = col - 1;
        float v = 0.f;
        if (gy >= 0 && gy < 256 && gx >= 0 && gx < 256)
            v = x[((size_t)(b*64 + chunk*8 + c))*HW + gy*256 + gx];
        xs[c][rr][col] = v;
    }
    __syncthreads();
    float acc[4][2];
    #pragma unroll
    for (int o = 0; o < 4; ++o){ acc[o][0]=0.f; acc[o][1]=0.f; }
    int j = tid;
    #pragma unroll
    for (int c = 0; c < 8; ++c){
        float vrow[4][3];
        #pragma unroll
        for (int rr = 0; rr < 4; ++rr){
            vrow[rr][0] = xs[c][rr][j];
            vrow[rr][1] = xs[c][rr][j+1];
            vrow[rr][2] = xs[c][rr][j+2];
        }
        #pragma unroll
        for (int o = 0; o < 4; ++o){
            const float* wr = wsm[o][c];
            #pragma unroll
            for (int ky = 0; ky < 3; ++ky){
                #pragma unroll
                for (int kx = 0; kx < 3; ++kx){
                    float wv = wr[ky*3+kx];
                    acc[o][0] += wv * vrow[ky][kx];
                    acc[o][1] += wv * vrow[ky+1][kx];
                }
            }
        }
    }
    #pragma unroll
    for (int o = 0; o < 4; ++o){
        size_t base = ((size_t)((chunk*4 + o)*4 + b))*HW;
        poff[base + (size_t)i0*256 + j]     = acc[o][0];
        poff[base + (size_t)(i0+1)*256 + j] = acc[o][1];
    }
}

// ---------------- offset reduce: sum 8 chunks + BN + tanh; also zero center planes ----------------
__global__ __launch_bounds__(256) void k_offred(const float* __restrict__ poff,
        const float* __restrict__ ogx, const float* __restrict__ ovx,
        const float* __restrict__ obx, const float* __restrict__ omx,
        const float* __restrict__ obbx,
        const float* __restrict__ ogy, const float* __restrict__ ovy,
        const float* __restrict__ oby, const float* __restrict__ omy,
        const float* __restrict__ obby,
        float* __restrict__ off0, float* __restrict__ off1){
    int idx = blockIdx.x*256 + threadIdx.x;   // 24*65536
    int px = idx & 65535;
    int t2 = idx >> 16;       // 0..23
    int b = t2 & 3;
    int o6 = t2 >> 2;         // 0..5
    if (o6 < 4){
        float s_ = 0.f;
        #pragma unroll
        for (int chunk = 0; chunk < 8; ++chunk)
            s_ += poff[((size_t)((chunk*4 + o6)*4 + b))*HW + px];
        int morph = o6 >> 1;
        int ch = (o6==0)?0:(o6==1)?2:(o6==2)?3:5;
        const float* og_ = morph? ogy:ogx; const float* ov_ = morph? ovy:ovx;
        const float* ob_ = morph? oby:obx; const float* om_ = morph? omy:omx;
        const float* obb_ = morph? obby:obbx;
        float sc = og_[ch]*rsqrtf(ov_[ch]+EPSV);
        float bi = (ob_[ch]-om_[ch])*sc + obb_[ch];
        int pl = (o6 & 1)*2;
        float* dst = (morph? off1:off0) + ((size_t)(b*3+pl))*HW;
        dst[px] = tanhf(s_*sc + bi);
    } else {
        float* dst = ((o6==5)? off1:off0) + ((size_t)(b*3+1))*HW;
        dst[px] = 0.f;
    }
}

// ---------------- conv0 via MFMA (verified) ----
__global__ __launch_bounds__(256) void k_conv0_mfma(
        const ushort_t* __restrict__ xbf, const ushort_t* __restrict__ w0bf,
        const float* __restrict__ g0, const float* __restrict__ b0,
        const float* __restrict__ m0, const float* __restrict__ v0,
        float* __restrict__ out){
    int b = blockIdx.y;
    int i = blockIdx.x;
    int wv = threadIdx.x >> 6;
    int lane = threadIdx.x & 63;
    int j0 = wv * 64;
    int l15 = lane & 15;
    int lhi = lane >> 4;
    f32x4 acc[4][4];
    #pragma unroll
    for (int mi = 0; mi < 4; ++mi)
        #pragma unroll
        for (int ni = 0; ni < 4; ++ni)
            acc[mi][ni] = (f32x4){0.f,0.f,0.f,0.f};

    for (int r = 0; r < 9; ++r){
        int dy = r/3 - 1, dx = r%3 - 1;
        int yy = i + dy;
        if (yy < 0 || yy >= TS) continue;
        const ushort_t* xrow = xbf + (((size_t)b*TS + yy)*XPITCH + 1)*64;
        const ushort_t* wrow = w0bf + (size_t)r*4096;
        #pragma unroll
        for (int kc = 0; kc < 2; ++kc){
            int c0 = kc*32 + lhi*8;
            bf16x8 af[4], bfr[4];
            #pragma unroll
            for (int mi = 0; mi < 4; ++mi)
                af[mi] = *(const bf16x8*)(wrow + (mi*16 + l15)*64 + c0);
            #pragma unroll
            for (int ni = 0; ni < 4; ++ni)
                bfr[ni] = *(const bf16x8*)(xrow + ((size_t)(j0 + ni*16 + l15 + dx))*64 + c0);
            #pragma unroll
            for (int mi = 0; mi < 4; ++mi)
                #pragma unroll
                for (int ni = 0; ni < 4; ++ni)
                    acc[mi][ni] = __builtin_amdgcn_mfma_f32_16x16x32_bf16(af[mi], bfr[ni], acc[mi][ni], 0, 0, 0);
        }
    }
    #pragma unroll
    for (int mi = 0; mi < 4; ++mi){
        #pragma unroll
        for (int reg = 0; reg < 4; ++reg){
            int o = mi*16 + lhi*4 + reg;
            float s = g0[o] * rsqrtf(v0[o] + EPSV);
            float bi = b0[o] - m0[o]*s;
            #pragma unroll
            for (int ni = 0; ni < 4; ++ni){
                int j = j0 + ni*16 + l15;
                float v = acc[mi][ni][reg]*s + bi;
                out[((size_t)(b*192 + o))*HW + i*TS + j] = silu_f(v);
            }
        }
    }
}

// ---------------- DSC: bilinear gather -> LDS bf16 -> MFMA (K=192 t-major), fused GN partials ----
template<int MORPH>
__global__ __launch_bounds__(256) void k_dsc2(const ushort_t* __restrict__ xbf, const float* __restrict__ offm,
        const ushort_t* __restrict__ wbf, const float* __restrict__ wb,
        float* __restrict__ outm, float* __restrict__ part){
    __shared__ __align__(16) ushort_t Vt[3*64*64];   // byte: t*8192 + j*128 + (c*2 ^ ((j&7)<<4))
    int b = blockIdx.z;
    int i = blockIdx.y;
    int j0 = blockIdx.x * 64;
    int tid = threadIdx.x;
    int lane16 = tid & 15;
    int pq = tid >> 4;
    const float fi = (float)i;

    #pragma unroll
    for (int it = 0; it < 12; ++it){
        int pair = it*16 + pq;
        int t = pair >> 6, jloc = pair & 63;
        float y, wx1, wx0;
        int x0i, x1i;
        if (MORPH == 0){
            int j = j0 + jloc;
            float off = offm[((size_t)(b*3 + t)*TS + i)*TS + j];
            y = fi + off;
            float vp = (t==0) ? -2.0f : ((t==1) ? -0.5f : 1.0f);
            float xf = fi + vp;
            float x0 = fminf(fmaxf(floorf(xf), 0.f), 255.f);
            float x1 = fminf(fmaxf(floorf(xf) + 1.f, 0.f), 255.f);
            wx1 = x1 - xf; wx0 = xf - x0;
            x0i = (int)x0; x1i = (int)x1;
        } else {
            int q = 3*(j0 + jloc) + t;
            int dl = q >> 8, jj = q & 255;
            float off = offm[((size_t)(b*3 + dl)*TS + i)*TS + jj];
            float vp = (dl==0) ? -2.0f : ((dl==1) ? -0.5f : 1.0f);
            y = fi + vp + off;
            wx1 = (i < 255) ? 1.f : 0.f; wx0 = 0.f;
            x0i = i; x1i = i;
        }
        float yf = floorf(y);
        float y0 = fminf(fmaxf(yf, 0.f), 255.f);
        float y1 = fminf(fmaxf(yf + 1.f, 0.f), 255.f);
        float wy1 = y1 - y, wy0 = y - y0;
        int y0i = (int)y0, y1i = (int)y1;
        int c0 = lane16*4;
        u16x4 a = *(const u16x4*)(xbf + ((size_t)y0i*XPITCH + 1 + x0i)*64 + c0);
        u16x4 c_ = *(const u16x4*)(xbf + ((size_t)y1i*XPITCH + 1 + x0i)*64 + c0);
        float v[4];
        if (MORPH == 0 && wx0 != 0.f){
            u16x4 bv = *(const u16x4*)(xbf + ((size_t)y0i*XPITCH + 1 + x1i)*64 + c0);
            u16x4 d  = *(const u16x4*)(xbf + ((size_t)y1i*XPITCH + 1 + x1i)*64 + c0);
            #pragma unroll
            for (int k = 0; k < 4; ++k)
                v[k] = wy1*(wx1*bf2f(a[k]) + wx0*bf2f(bv[k]))
                     + wy0*(wx1*bf2f(c_[k]) + wx0*bf2f(d[k]));
        } else {
            #pragma unroll
            for (int k = 0; k < 4; ++k)
                v[k] = wx1*(wy1*bf2f(a[k]) + wy0*bf2f(c_[k]));
        }
        unsigned int lo = (unsigned int)f2bf(v[0]) | ((unsigned int)f2bf(v[1]) << 16);
        unsigned int hi = (unsigned int)f2bf(v[2]) | ((unsigned int)f2bf(v[3]) << 16);
        int cbyte = (c0*2) ^ ((jloc & 7) << 4);
        uint2 pk; pk.x = lo; pk.y = hi;
        *(uint2*)((char*)Vt + t*8192 + jloc*128 + cbyte) = pk;
    }
    __syncthreads();

    int wv = tid >> 6;
    int lane = tid & 63;
    int l15 = lane & 15, lhi = lane >> 4;
    int mi = wv;
    f32x4 acc[4];
    #pragma unroll
    for (int ni = 0; ni < 4; ++ni) acc[ni] = (f32x4){0.f,0.f,0.f,0.f};
    bf16x8 af[6];
    #pragma unroll
    for (int ks = 0; ks < 6; ++ks)
        af[ks] = *(const bf16x8*)(wbf + (mi*16 + l15)*192 + ks*32 + lhi*8);
    #pragma unroll
    for (int ks = 0; ks < 6; ++ks){
        int t = ks >> 1;
        int cbyte = ((ks & 1)*32 + lhi*8)*2;
        #pragma unroll
        for (int ni = 0; ni < 4; ++ni){
            int j = ni*16 + l15;
            bf16x8 bfr = *(const bf16x8*)((char*)Vt + t*8192 + j*128 + (cbyte ^ ((j & 7) << 4)));
            acc[ni] = __builtin_amdgcn_mfma_f32_16x16x32_bf16(af[ks], bfr, acc[ni], 0, 0, 0);
        }
    }
    float rsum[4], rsq[4];
    #pragma unroll
    for (int reg = 0; reg < 4; ++reg){
        int o = mi*16 + lhi*4 + reg;
        float bias = wb[o];
        float rs = 0.f, rq = 0.f;
        #pragma unroll
        for (int ni = 0; ni < 4; ++ni){
            int j = j0 + ni*16 + l15;
            float val = acc[ni][reg] + bias;
            outm[(size_t)b*192*HW + (size_t)o*HW + i*TS + j] = val;
            rs += val; rq += val*val;
        }
        #pragma unroll
        for (int m = 1; m < 16; m <<= 1){
            rs += __shfl_xor(rs, m, 64);
            rq += __shfl_xor(rq, m, 64);
        }
        rsum[reg] = rs; rsq[reg] = rq;
    }
    if (l15 == 0){
        float ts = rsum[0]+rsum[1]+rsum[2]+rsum[3];
        float tq = rsq[0]+rsq[1]+rsq[2]+rsq[3];
        int g = mi*4 + lhi;
        size_t slot = (((size_t)(MORPH*4 + b)*16 + g)*1024) + (blockIdx.y*4 + blockIdx.x);
        part[slot*2]   = ts;
        part[slot*2+1] = tq;
    }
}

// ---------------- GN final: reduce 1024 partials per (m,b,g) ----------------
__global__ __launch_bounds__(256) void k_gnfinal2(const float* __restrict__ part, float* __restrict__ stats){
    int slot = blockIdx.x;  // 0..127
    float s = 0.f, q = 0.f;
    for (int k = threadIdx.x; k < 1024; k += 256){
        s += part[((size_t)slot*1024 + k)*2];
        q += part[((size_t)slot*1024 + k)*2 + 1];
    }
    #pragma unroll
    for (int d = 32; d > 0; d >>= 1){ s += __shfl_down(s, d, 64); q += __shfl_down(q, d, 64); }
    __shared__ float rs[4], rq[4];
    int lane = threadIdx.x & 63, wv = threadIdx.x >> 6;
    if (lane == 0){ rs[wv] = s; rq[wv] = q; }
    __syncthreads();
    if (threadIdx.x == 0){
        float S = rs[0]+rs[1]+rs[2]+rs[3];
        float Q = rq[0]+rq[1]+rq[2]+rq[3];
        float inv = 1.f/262144.f;
        float mean = S*inv;
        float var = Q*inv - mean*mean;
        stats[slot*2] = mean;
        stats[slot*2+1] = rsqrtf(var + EPSV);
    }
}

__global__ __launch_bounds__(256) void k_gnapply(float* __restrict__ dout, const float* __restrict__ stats,
        const float* __restrict__ ggx, const float* __restrict__ gbx,
        const float* __restrict__ ggy, const float* __restrict__ gby){
    int idx = blockIdx.x*256 + threadIdx.x;
    int pix4 = idx & 16383;
    int chb = idx >> 14;
    int ch = chb & 127;
    int b = chb >> 7;
    int m = ch >> 6;
    int cc = ch & 63;
    int g = cc >> 2;
    const float* gg = m ? ggy : ggx;
    const float* gb = m ? gby : gbx;
    int si = ((m*4 + b)*16 + g)*2;
    float mean = stats[si], rsig = stats[si+1];
    float sc = rsig * gg[cc];
    float bi = gb[cc] - mean*sc;
    float4* ptr = (float4*)(dout + ((size_t)(b*192 + 64 + ch))*HW) + pix4;
    float4 v = *ptr;
    v.x = silu_f(v.x*sc + bi); v.y = silu_f(v.y*sc + bi);
    v.z = silu_f(v.z*sc + bi); v.w = silu_f(v.w*sc + bi);
    *ptr = v;
}

extern "C" void kernel_launch(void* const* d_in, const int* in_sizes, int n_in,
                              void* d_out, int out_size, void* d_ws, size_t ws_size,
                              hipStream_t stream){
    const float* x    = (const float*)d_in[0];
    const float* w0   = (const float*)d_in[1];
    const float* g0   = (const float*)d_in[2];
    const float* b0   = (const float*)d_in[3];
    const float* m0   = (const float*)d_in[4];
    const float* v0   = (const float*)d_in[5];
    const float* owx  = (const float*)d_in[6];
    const float* obx  = (const float*)d_in[7];
    const float* ogx  = (const float*)d_in[8];
    const float* obbx = (const float*)d_in[9];
    const float* omx  = (const float*)d_in[10];
    const float* ovx  = (const float*)d_in[11];
    const float* wx   = (const float*)d_in[12];
    const float* bwx  = (const float*)d_in[13];
    const float* ggx  = (const float*)d_in[14];
    const float* gbx  = (const float*)d_in[15];
    const float* owy  = (const float*)d_in[16];
    const float* oby  = (const float*)d_in[17];
    const float* ogy  = (const float*)d_in[18];
    const float* obby = (const float*)d_in[19];
    const float* omy  = (const float*)d_in[20];
    const float* ovy  = (const float*)d_in[21];
    const float* wy   = (const float*)d_in[22];
    const float* bwy  = (const float*)d_in[23];
    const float* ggy  = (const float*)d_in[24];
    const float* gby  = (const float*)d_in[25];

    float* out = (float*)d_out;
    // ws layout (bytes):
    //   xbf   @ 0          : 33,816,576
    //   w0bf  @ 33,816,576 : 73,728
    //   wbfx  @ 33,890,304 : 24,576
    //   wbfy  @ 33,914,880 : 24,576
    //   off0  @ 33,939,456 : 3,145,728
    //   off1  @ 37,085,184 : 3,145,728
    //   part  @ 40,230,912 : 1,048,576
    //   stats @ 41,279,488 : 1,024
    //   poff  @ 41,280,512 : 33,554,432
    ushort_t* xbf  = (ushort_t*)d_ws;
    ushort_t* w0bf = (ushort_t*)((char*)d_ws + 33816576);
    ushort_t* wbfx = (ushort_t*)((char*)d_ws + 33890304);
    ushort_t* wbfy = (ushort_t*)((char*)d_ws + 33914880);
    float* off0  = (float*)((char*)d_ws + 33939456);
    float* off1  = (float*)((char*)d_ws + 37085184);
    float* part  = (float*)((char*)d_ws + 40230912);
    float* stats = (float*)((char*)d_ws + 41279488);
    float* poff  = (float*)((char*)d_ws + 41280512);

    k_xbf<<<4096, 256, 0, stream>>>(x, xbf);
    k_halo<<<dim3(256,4), 128, 0, stream>>>(xbf);
    k_wrepack<<<144, 256, 0, stream>>>(w0, w0bf);
    k_wdsc<<<96, 256, 0, stream>>>(wx, wy, wbfx, wbfy);
    k_offp<<<dim3(128,32), 256, 0, stream>>>(x, owx, owy, poff);
    k_offred<<<6144, 256, 0, stream>>>(poff,
        ogx, ovx, obx, omx, obbx,
        ogy, ovy, oby, omy, obby,
        off0, off1);
    k_conv0_mfma<<<dim3(256,4), 256, 0, stream>>>(xbf, w0bf, g0, b0, m0, v0, out);
    k_dsc2<0><<<dim3(4,256,4), 256, 0, stream>>>(xbf, off0, wbfx, bwx, out + (size_t)64*HW, part);
    k_dsc2<1><<<dim3(4,256,4), 256, 0, stream>>>(xbf, off1, wbfy, bwy, out + (size_t)128*HW, part);
    k_gnfinal2<<<128, 256, 0, stream>>>(part, stats);
    k_gnapply<<<32768, 256, 0, stream>>>(out, stats, ggx, gbx, ggy, gby);
}